// Round 1
// baseline (608.583 us; speedup 1.0000x reference)
//
#include <hip/hip_runtime.h>
#include <hip/hip_bf16.h>

typedef unsigned short u16;
typedef __attribute__((ext_vector_type(8))) short short8;
typedef __attribute__((ext_vector_type(4))) float f32x4;

#define BM 128
#define BN 128
#define BK 32

__device__ __forceinline__ u16 f2bf(float x) {
    union { float f; unsigned int u; } v; v.f = x;
    unsigned int r = v.u + 0x7fffu + ((v.u >> 16) & 1u);
    return (u16)(r >> 16);
}
__device__ __forceinline__ float bf2f(u16 h) {
    union { unsigned int u; float f; } v; v.u = ((unsigned int)h) << 16;
    return v.f;
}

// ---------------------------------------------------------------------------
// Transpose + (optional) split: in fp32 [R][C] -> out bf16 [C][R] (hi, lo?)
// ---------------------------------------------------------------------------
__global__ __launch_bounds__(256)
void transpose_split(const float* __restrict__ in, u16* __restrict__ out_hi,
                     u16* __restrict__ out_lo, int R, int C,
                     long long in_stride, long long out_stride) {
    const int b = blockIdx.z;
    in += (size_t)b * in_stride;
    out_hi += (size_t)b * out_stride;
    if (out_lo) out_lo += (size_t)b * out_stride;

    __shared__ float tile[32][33];
    const int r0 = blockIdx.y * 32, c0 = blockIdx.x * 32;
    const int t = threadIdx.x;
    const int tr = t >> 5, tc = t & 31;   // tr 0..7, tc 0..31
    for (int i = 0; i < 4; i++)
        tile[tr + i * 8][tc] = in[(size_t)(r0 + tr + i * 8) * C + c0 + tc];
    __syncthreads();
    for (int i = 0; i < 4; i++) {
        float v = tile[tc][tr + i * 8];
        size_t idx = (size_t)(c0 + tr + i * 8) * R + r0 + tc;
        u16 h = f2bf(v);
        out_hi[idx] = h;
        if (out_lo) out_lo[idx] = f2bf(v - bf2f(h));
    }
}

// ---------------------------------------------------------------------------
// Generic B^T-layout GEMM: C[m][n] = sum_k A[m][k] * B[n][k]
//  A_F32: A is fp32, split to hi/lo in staging; else A is bf16 hi (+lo)
//  B_F32: same for B
//  SPLIT: 3-MFMA error-corrected product (hh + h*lo + lo*h)
//  EPI: 0 = fp32 C store; 1 = fp32 C store + mask[n] add; 2 = bf16 hi/lo store
//  lda = ldb = K, ldc = N (true for all uses here)
// ---------------------------------------------------------------------------
template<bool A_F32, bool B_F32, bool SPLIT, int EPI>
__global__ __launch_bounds__(256)
void gemm_bt(const void* __restrict__ Ap, const void* __restrict__ Alop,
             const void* __restrict__ Bp, const void* __restrict__ Blop,
             float* __restrict__ Cf, u16* __restrict__ Chi, u16* __restrict__ Clo,
             const float* __restrict__ mask,
             int M, int N, int K,
             long long batchA, long long batchB, long long batchC, long long batchMask) {
    const int b = blockIdx.z;
    const int m0 = blockIdx.y * BM;
    const int n0 = blockIdx.x * BN;
    const int t = threadIdx.x;
    const int lane = t & 63, wv = t >> 6;
    const int wm = (wv >> 1) * 64, wn = (wv & 1) * 64;

    __shared__ alignas(16) u16 sAh[BM][BK];
    __shared__ alignas(16) u16 sAl[BM][BK];
    __shared__ alignas(16) u16 sBh[BN][BK];
    __shared__ alignas(16) u16 sBl[BN][BK];

    f32x4 acc[4][4];
    for (int mi = 0; mi < 4; mi++)
        for (int ni = 0; ni < 4; ni++)
            for (int r = 0; r < 4; r++) acc[mi][ni][r] = 0.0f;

    for (int k0 = 0; k0 < K; k0 += BK) {
        // ---- stage A ----
        if constexpr (A_F32) {
            const float* Ag = (const float*)Ap + (size_t)b * batchA;
            const int r = t >> 3, c = (t & 7) * 4;
            for (int i = 0; i < 4; i++) {
                const int row = r + i * 32;
                const float4 v = *(const float4*)&Ag[(size_t)(m0 + row) * K + k0 + c];
                u16 h0 = f2bf(v.x), h1 = f2bf(v.y), h2 = f2bf(v.z), h3 = f2bf(v.w);
                ushort4 hv; hv.x = h0; hv.y = h1; hv.z = h2; hv.w = h3;
                *(ushort4*)&sAh[row][c] = hv;
                if constexpr (SPLIT) {
                    ushort4 lv;
                    lv.x = f2bf(v.x - bf2f(h0)); lv.y = f2bf(v.y - bf2f(h1));
                    lv.z = f2bf(v.z - bf2f(h2)); lv.w = f2bf(v.w - bf2f(h3));
                    *(ushort4*)&sAl[row][c] = lv;
                }
            }
        } else {
            const u16* Ah = (const u16*)Ap + (size_t)b * batchA;
            const int r = t >> 2, c = (t & 3) * 8;
            for (int i = 0; i < 2; i++) {
                const int row = r + i * 64;
                *(uint4*)&sAh[row][c] = *(const uint4*)&Ah[(size_t)(m0 + row) * K + k0 + c];
                if constexpr (SPLIT) {
                    const u16* Al = (const u16*)Alop + (size_t)b * batchA;
                    *(uint4*)&sAl[row][c] = *(const uint4*)&Al[(size_t)(m0 + row) * K + k0 + c];
                }
            }
        }
        // ---- stage B ----
        if constexpr (B_F32) {
            const float* Bg = (const float*)Bp + (size_t)b * batchB;
            const int r = t >> 3, c = (t & 7) * 4;
            for (int i = 0; i < 4; i++) {
                const int row = r + i * 32;
                const float4 v = *(const float4*)&Bg[(size_t)(n0 + row) * K + k0 + c];
                u16 h0 = f2bf(v.x), h1 = f2bf(v.y), h2 = f2bf(v.z), h3 = f2bf(v.w);
                ushort4 hv; hv.x = h0; hv.y = h1; hv.z = h2; hv.w = h3;
                *(ushort4*)&sBh[row][c] = hv;
                if constexpr (SPLIT) {
                    ushort4 lv;
                    lv.x = f2bf(v.x - bf2f(h0)); lv.y = f2bf(v.y - bf2f(h1));
                    lv.z = f2bf(v.z - bf2f(h2)); lv.w = f2bf(v.w - bf2f(h3));
                    *(ushort4*)&sBl[row][c] = lv;
                }
            }
        } else {
            const u16* Bh = (const u16*)Bp + (size_t)b * batchB;
            const int r = t >> 2, c = (t & 3) * 8;
            for (int i = 0; i < 2; i++) {
                const int row = r + i * 64;
                *(uint4*)&sBh[row][c] = *(const uint4*)&Bh[(size_t)(n0 + row) * K + k0 + c];
                if constexpr (SPLIT) {
                    const u16* Bl = (const u16*)Blop + (size_t)b * batchB;
                    *(uint4*)&sBl[row][c] = *(const uint4*)&Bl[(size_t)(n0 + row) * K + k0 + c];
                }
            }
        }
        __syncthreads();

        // ---- fragments + MFMA ----
        const int fr = lane & 15, fq = (lane >> 4) * 8;
        short8 ah[4], al[4], bh[4], bl[4];
        for (int i = 0; i < 4; i++) {
            ah[i] = *(const short8*)&sAh[wm + i * 16 + fr][fq];
            bh[i] = *(const short8*)&sBh[wn + i * 16 + fr][fq];
            if constexpr (SPLIT) {
                al[i] = *(const short8*)&sAl[wm + i * 16 + fr][fq];
                bl[i] = *(const short8*)&sBl[wn + i * 16 + fr][fq];
            }
        }
        for (int mi = 0; mi < 4; mi++)
            for (int ni = 0; ni < 4; ni++) {
                acc[mi][ni] = __builtin_amdgcn_mfma_f32_16x16x32_bf16(ah[mi], bh[ni], acc[mi][ni], 0, 0, 0);
                if constexpr (SPLIT) {
                    acc[mi][ni] = __builtin_amdgcn_mfma_f32_16x16x32_bf16(ah[mi], bl[ni], acc[mi][ni], 0, 0, 0);
                    acc[mi][ni] = __builtin_amdgcn_mfma_f32_16x16x32_bf16(al[mi], bh[ni], acc[mi][ni], 0, 0, 0);
                }
            }
        __syncthreads();
    }

    // ---- epilogue ----
    const int fr = lane & 15, q4 = (lane >> 4) * 4;
    for (int mi = 0; mi < 4; mi++)
        for (int ni = 0; ni < 4; ni++) {
            const int col = n0 + wn + ni * 16 + fr;
            float mv = 0.0f;
            if constexpr (EPI == 1) mv = mask[(size_t)b * batchMask + col];
            for (int r = 0; r < 4; r++) {
                const int row = m0 + wm + mi * 16 + q4 + r;
                float v = acc[mi][ni][r];
                const size_t idx = (size_t)b * batchC + (size_t)row * N + col;
                if constexpr (EPI == 0) {
                    Cf[idx] = v;
                } else if constexpr (EPI == 1) {
                    Cf[idx] = v + mv;
                } else {
                    u16 h = f2bf(v);
                    Chi[idx] = h;
                    Clo[idx] = f2bf(v - bf2f(h));
                }
            }
        }
}

// ---------------------------------------------------------------------------
// Row softmax over 1024 cols, in place (fp32) + bf16 copy for the PV GEMM
// ---------------------------------------------------------------------------
__global__ __launch_bounds__(256)
void softmax_rows(float* __restrict__ w, u16* __restrict__ sb) {
    const size_t row = blockIdx.x;
    float* p = w + row * 1024;
    const int t = threadIdx.x;
    const int wv = t >> 6, ln = t & 63;

    float4 v = *(const float4*)&p[t * 4];
    float m = fmaxf(fmaxf(v.x, v.y), fmaxf(v.z, v.w));
    for (int o = 32; o > 0; o >>= 1) m = fmaxf(m, __shfl_down(m, o));
    __shared__ float redm[4];
    if (ln == 0) redm[wv] = m;
    __syncthreads();
    m = fmaxf(fmaxf(redm[0], redm[1]), fmaxf(redm[2], redm[3]));

    float e0 = __expf(v.x - m), e1 = __expf(v.y - m);
    float e2 = __expf(v.z - m), e3 = __expf(v.w - m);
    float s = e0 + e1 + e2 + e3;
    for (int o = 32; o > 0; o >>= 1) s += __shfl_down(s, o);
    __shared__ float reds[4];
    if (ln == 0) reds[wv] = s;
    __syncthreads();
    s = reds[0] + reds[1] + reds[2] + reds[3];
    const float inv = 1.0f / s;

    float4 o4; o4.x = e0 * inv; o4.y = e1 * inv; o4.z = e2 * inv; o4.w = e3 * inv;
    *(float4*)&p[t * 4] = o4;
    ushort4 h4; h4.x = f2bf(o4.x); h4.y = f2bf(o4.y); h4.z = f2bf(o4.z); h4.w = f2bf(o4.w);
    *(ushort4*)&sb[row * 1024 + t * 4] = h4;
}

// ---------------------------------------------------------------------------
extern "C" void kernel_launch(void* const* d_in, const int* in_sizes, int n_in,
                              void* d_out, int out_size, void* d_ws, size_t ws_size,
                              hipStream_t stream) {
    const int B = 16, T = 1024, D = 1024;
    const long long MAT = (long long)T * D;      // 1M elems

    const float* query  = (const float*)d_in[0]; // [B,TQ,DQ]
    const float* keys   = (const float*)d_in[1]; // [B,TK,DK]
    const float* values = (const float*)d_in[2]; // [B,TK,DV]
    const float* W      = (const float*)d_in[3]; // [DQ,DK]
    const float* mask   = (const float*)d_in[4]; // [B,TK]

    float* out = (float*)d_out;
    float* score_f = out;                        // [B,TQ,TK]
    float* ctx_f   = out + (size_t)B * MAT;      // [B,TQ,DV]

    char* ws = (char*)d_ws;
    u16* wt_hi = (u16*)ws;                 ws += (size_t)MAT * 2;        // W^T hi  [e][d]
    u16* wt_lo = (u16*)ws;                 ws += (size_t)MAT * 2;        // W^T lo
    u16* vt    = (u16*)ws;                 ws += (size_t)B * MAT * 2;    // V^T bf16 [b][v][k]
    u16* qw_hi = (u16*)ws;                 ws += (size_t)B * MAT * 2;    // qW hi   [b*q][e]
    u16* qw_lo = (u16*)ws;                 ws += (size_t)B * MAT * 2;    // qW lo
    u16* sc_bf = (u16*)ws;                 ws += (size_t)B * MAT * 2;    // score bf16

    dim3 blk(256);

    // Prep: W^T split (exact to 2^-17), V^T bf16
    transpose_split<<<dim3(32, 32, 1), blk, 0, stream>>>(W, wt_hi, wt_lo, D, D, 0, 0);
    transpose_split<<<dim3(32, 32, B), blk, 0, stream>>>(values, vt, nullptr, T, D, MAT, MAT);

    // GEMM1: qW = query @ W  (fp32-split x bf16-split, error-corrected)
    gemm_bt<true, false, true, 2><<<dim3(8, 128, 1), blk, 0, stream>>>(
        query, nullptr, wt_hi, wt_lo, nullptr, qw_hi, qw_lo, nullptr,
        B * T, D, D, 0, 0, 0, 0);

    // GEMM2: logits = qW @ keys^T + mask  -> d_out score region (fp32)
    gemm_bt<false, true, true, 1><<<dim3(8, 8, B), blk, 0, stream>>>(
        qw_hi, qw_lo, keys, nullptr, score_f, nullptr, nullptr, mask,
        T, T, D, MAT, MAT, MAT, T);

    // Softmax rows, in place + bf16 copy
    softmax_rows<<<B * T, blk, 0, stream>>>(score_f, sc_bf);

    // GEMM3: ctx = score @ values (plain bf16)
    gemm_bt<false, false, false, 0><<<dim3(8, 8, B), blk, 0, stream>>>(
        sc_bf, nullptr, vt, nullptr, ctx_f, nullptr, nullptr, nullptr,
        T, D, T, MAT, MAT, MAT, 0);
}

// Round 2
// 591.923 us; speedup vs baseline: 1.0281x; 1.0281x over previous
//
#include <hip/hip_runtime.h>
#include <hip/hip_bf16.h>

typedef unsigned short u16;
typedef __attribute__((ext_vector_type(8))) short short8;
typedef __attribute__((ext_vector_type(4))) float f32x4;

#define BM 128
#define BN 128
#define BK 32

__device__ __forceinline__ u16 f2bf(float x) {
    union { float f; unsigned int u; } v; v.f = x;
    unsigned int r = v.u + 0x7fffu + ((v.u >> 16) & 1u);
    return (u16)(r >> 16);
}
__device__ __forceinline__ float bf2f(u16 h) {
    union { unsigned int u; float f; } v; v.u = ((unsigned int)h) << 16;
    return v.f;
}

// async global->LDS, 16B per lane; LDS dest is wave-uniform base + lane*16
__device__ __forceinline__ void gl2lds16(const u16* g, const u16* l) {
    __builtin_amdgcn_global_load_lds(
        (const __attribute__((address_space(1))) unsigned int*)g,
        (__attribute__((address_space(3))) unsigned int*)l, 16, 0, 0);
}

// ---------------------------------------------------------------------------
// Elementwise split: fp32 -> bf16 hi + bf16 lo (residual), 8 elems/thread
// ---------------------------------------------------------------------------
__global__ __launch_bounds__(256)
void split_f32(const float* __restrict__ in, u16* __restrict__ hi,
               u16* __restrict__ lo, long long n) {
    long long i = ((long long)blockIdx.x * 256 + threadIdx.x) * 8;
    if (i >= n) return;
    float4 a = *(const float4*)&in[i];
    float4 b = *(const float4*)&in[i + 4];
    union { ushort4 v[2]; uint4 q; } H, L;
    float av[8] = {a.x, a.y, a.z, a.w, b.x, b.y, b.z, b.w};
    u16 hh[8];
#pragma unroll
    for (int j = 0; j < 8; j++) hh[j] = f2bf(av[j]);
    H.v[0] = make_ushort4(hh[0], hh[1], hh[2], hh[3]);
    H.v[1] = make_ushort4(hh[4], hh[5], hh[6], hh[7]);
    u16 ll[8];
#pragma unroll
    for (int j = 0; j < 8; j++) ll[j] = f2bf(av[j] - bf2f(hh[j]));
    L.v[0] = make_ushort4(ll[0], ll[1], ll[2], ll[3]);
    L.v[1] = make_ushort4(ll[4], ll[5], ll[6], ll[7]);
    *(uint4*)&hi[i] = H.q;
    *(uint4*)&lo[i] = L.q;
}

// ---------------------------------------------------------------------------
// Transpose + (optional) split: fp32 [R][C] -> bf16 [C][R] (hi, lo?)
// ---------------------------------------------------------------------------
__global__ __launch_bounds__(256)
void transpose_split(const float* __restrict__ in, u16* __restrict__ out_hi,
                     u16* __restrict__ out_lo, int R, int C,
                     long long in_stride, long long out_stride) {
    const int b = blockIdx.z;
    in += (size_t)b * in_stride;
    out_hi += (size_t)b * out_stride;
    if (out_lo) out_lo += (size_t)b * out_stride;

    __shared__ float tile[32][33];
    const int r0 = blockIdx.y * 32, c0 = blockIdx.x * 32;
    const int t = threadIdx.x;
    const int tr = t >> 5, tc = t & 31;
    for (int i = 0; i < 4; i++)
        tile[tr + i * 8][tc] = in[(size_t)(r0 + tr + i * 8) * C + c0 + tc];
    __syncthreads();
    for (int i = 0; i < 4; i++) {
        float v = tile[tc][tr + i * 8];
        size_t idx = (size_t)(c0 + tr + i * 8) * R + r0 + tc;
        u16 h = f2bf(v);
        out_hi[idx] = h;
        if (out_lo) out_lo[idx] = f2bf(v - bf2f(h));
    }
}

// ---------------------------------------------------------------------------
// B^T-layout bf16 GEMM, global_load_lds staging:
//   C[m][n] = sum_k A[m][k]*B[n][k]
//   SPLIT: 3-MFMA error-corrected (Ah*Bh + Ah*Bl + Al*Bh)
//   EPI: 0 = fp32 store; 1 = fp32 + mask[n]; 2 = bf16 hi/lo split store
//   lda = ldb = K (true for all uses here), ldc = N
// ---------------------------------------------------------------------------
template<bool SPLIT, int EPI>
__global__ __launch_bounds__(256)
void gemm_bt(const u16* __restrict__ Ah_, const u16* __restrict__ Al_,
             const u16* __restrict__ Bh_, const u16* __restrict__ Bl_,
             float* __restrict__ Cf, u16* __restrict__ Chi, u16* __restrict__ Clo,
             const float* __restrict__ mask,
             int M, int N, int K,
             long long batchA, long long batchB, long long batchC) {
    const int b = blockIdx.z;
    const int m0 = blockIdx.y * BM;
    const int n0 = blockIdx.x * BN;
    const int t = threadIdx.x;
    const int lane = t & 63, wv = t >> 6;
    const int wm = (wv >> 1) * 64, wn = (wv & 1) * 64;

    const u16* Ah = Ah_ + (size_t)b * batchA;
    const u16* Bh = Bh_ + (size_t)b * batchB;
    const u16* Al = SPLIT ? (Al_ + (size_t)b * batchA) : nullptr;
    const u16* Bl = SPLIT ? (Bl_ + (size_t)b * batchB) : nullptr;

    __shared__ alignas(16) u16 sAh[BM][BK];
    __shared__ alignas(16) u16 sAl[BM][BK];
    __shared__ alignas(16) u16 sBh[BN][BK];
    __shared__ alignas(16) u16 sBl[BN][BK];

    f32x4 acc[4][4];
    for (int mi = 0; mi < 4; mi++)
        for (int ni = 0; ni < 4; ni++)
            for (int r = 0; r < 4; r++) acc[mi][ni][r] = 0.0f;

    const int lrow = lane >> 2;        // 0..15
    const int lcol = (lane & 3) * 8;   // 0,8,16,24

    for (int k0 = 0; k0 < K; k0 += BK) {
#pragma unroll
        for (int i = 0; i < 2; i++) {
            const int r0 = (wv + 4 * i) * 16;       // wave-uniform row block
            const size_t ga = (size_t)(m0 + r0 + lrow) * K + k0 + lcol;
            const size_t gb = (size_t)(n0 + r0 + lrow) * K + k0 + lcol;
            gl2lds16(&Ah[ga], &sAh[r0][0]);
            gl2lds16(&Bh[gb], &sBh[r0][0]);
            if constexpr (SPLIT) {
                gl2lds16(&Al[ga], &sAl[r0][0]);
                gl2lds16(&Bl[gb], &sBl[r0][0]);
            }
        }
        __syncthreads();

        const int fr = lane & 15, fq = (lane >> 4) * 8;
        short8 ah[4], al[4], bh[4], bl[4];
#pragma unroll
        for (int i = 0; i < 4; i++) {
            ah[i] = *(const short8*)&sAh[wm + i * 16 + fr][fq];
            bh[i] = *(const short8*)&sBh[wn + i * 16 + fr][fq];
            if constexpr (SPLIT) {
                al[i] = *(const short8*)&sAl[wm + i * 16 + fr][fq];
                bl[i] = *(const short8*)&sBl[wn + i * 16 + fr][fq];
            }
        }
#pragma unroll
        for (int mi = 0; mi < 4; mi++)
#pragma unroll
            for (int ni = 0; ni < 4; ni++) {
                acc[mi][ni] = __builtin_amdgcn_mfma_f32_16x16x32_bf16(ah[mi], bh[ni], acc[mi][ni], 0, 0, 0);
                if constexpr (SPLIT) {
                    acc[mi][ni] = __builtin_amdgcn_mfma_f32_16x16x32_bf16(ah[mi], bl[ni], acc[mi][ni], 0, 0, 0);
                    acc[mi][ni] = __builtin_amdgcn_mfma_f32_16x16x32_bf16(al[mi], bh[ni], acc[mi][ni], 0, 0, 0);
                }
            }
        __syncthreads();
    }

    const int fr = lane & 15, q4 = (lane >> 4) * 4;
    for (int mi = 0; mi < 4; mi++)
        for (int ni = 0; ni < 4; ni++) {
            const int col = n0 + wn + ni * 16 + fr;
            float mv = 0.0f;
            if constexpr (EPI == 1) mv = mask[(size_t)b * N + col];
            for (int r = 0; r < 4; r++) {
                const int row = m0 + wm + mi * 16 + q4 + r;
                float v = acc[mi][ni][r];
                const size_t idx = (size_t)b * batchC + (size_t)row * N + col;
                if constexpr (EPI == 0) {
                    Cf[idx] = v;
                } else if constexpr (EPI == 1) {
                    Cf[idx] = v + mv;
                } else {
                    u16 h = f2bf(v);
                    Chi[idx] = h;
                    Clo[idx] = f2bf(v - bf2f(h));
                }
            }
        }
}

// ---------------------------------------------------------------------------
// Row softmax over 1024 cols, in place (fp32) + bf16 copy for the PV GEMM
// ---------------------------------------------------------------------------
__global__ __launch_bounds__(256)
void softmax_rows(float* __restrict__ w, u16* __restrict__ sb) {
    const size_t row = blockIdx.x;
    float* p = w + row * 1024;
    const int t = threadIdx.x;
    const int wv = t >> 6, ln = t & 63;

    float4 v = *(const float4*)&p[t * 4];
    float m = fmaxf(fmaxf(v.x, v.y), fmaxf(v.z, v.w));
    for (int o = 32; o > 0; o >>= 1) m = fmaxf(m, __shfl_down(m, o));
    __shared__ float redm[4];
    if (ln == 0) redm[wv] = m;
    __syncthreads();
    m = fmaxf(fmaxf(redm[0], redm[1]), fmaxf(redm[2], redm[3]));

    float e0 = __expf(v.x - m), e1 = __expf(v.y - m);
    float e2 = __expf(v.z - m), e3 = __expf(v.w - m);
    float s = e0 + e1 + e2 + e3;
    for (int o = 32; o > 0; o >>= 1) s += __shfl_down(s, o);
    __shared__ float reds[4];
    if (ln == 0) reds[wv] = s;
    __syncthreads();
    s = reds[0] + reds[1] + reds[2] + reds[3];
    const float inv = 1.0f / s;

    float4 o4; o4.x = e0 * inv; o4.y = e1 * inv; o4.z = e2 * inv; o4.w = e3 * inv;
    *(float4*)&p[t * 4] = o4;
    ushort4 h4; h4.x = f2bf(o4.x); h4.y = f2bf(o4.y); h4.z = f2bf(o4.z); h4.w = f2bf(o4.w);
    *(ushort4*)&sb[row * 1024 + t * 4] = h4;
}

// ---------------------------------------------------------------------------
extern "C" void kernel_launch(void* const* d_in, const int* in_sizes, int n_in,
                              void* d_out, int out_size, void* d_ws, size_t ws_size,
                              hipStream_t stream) {
    const int B = 16, T = 1024, D = 1024;
    const long long MAT = (long long)T * D;      // 1M elems
    const long long BT = (long long)B * MAT;     // 16M elems

    const float* query  = (const float*)d_in[0]; // [B,TQ,DQ]
    const float* keys   = (const float*)d_in[1]; // [B,TK,DK]
    const float* values = (const float*)d_in[2]; // [B,TK,DV]
    const float* W      = (const float*)d_in[3]; // [DQ,DK]
    const float* mask   = (const float*)d_in[4]; // [B,TK]

    float* out = (float*)d_out;
    float* score_f = out;                        // [B,TQ,TK]
    float* ctx_f   = out + (size_t)BT;           // [B,TQ,DV]

    // Workspace (132 MB), with stream-order aliasing of region A:
    //   A (64 MB): q_hi/lo -> k_hi/lo -> vt (32MB) + sc_bf (32MB)
    //   Q (64 MB): qw_hi/lo
    //   Wt (4 MB): wt_hi/lo
    char* ws = (char*)d_ws;
    u16* regA  = (u16*)ws;                 ws += (size_t)BT * 2 * 2;    // 64 MB
    u16* qw_hi = (u16*)ws;                 ws += (size_t)BT * 2;        // 32 MB
    u16* qw_lo = (u16*)ws;                 ws += (size_t)BT * 2;        // 32 MB
    u16* wt_hi = (u16*)ws;                 ws += (size_t)MAT * 2;       // 2 MB
    u16* wt_lo = (u16*)ws;                 ws += (size_t)MAT * 2;       // 2 MB

    u16* q_hi = regA,       *q_lo = regA + BT;   // phase 1
    u16* k_hi = regA,       *k_lo = regA + BT;   // phase 2 (after GEMM1)
    u16* vt   = regA,       *sc_bf = regA + BT;  // phase 3 (after GEMM2)

    dim3 blk(256);

    // W^T split (exact to 2^-17)
    transpose_split<<<dim3(32, 32, 1), blk, 0, stream>>>(W, wt_hi, wt_lo, D, D, 0, 0);
    // query split (row-major kept: A operand of GEMM1)
    split_f32<<<dim3((unsigned)(BT / 2048)), blk, 0, stream>>>(query, q_hi, q_lo, BT);

    // GEMM1: qW = query @ W   -> qw hi/lo
    gemm_bt<true, 2><<<dim3(8, 128, 1), blk, 0, stream>>>(
        q_hi, q_lo, wt_hi, wt_lo, nullptr, qw_hi, qw_lo, nullptr,
        B * T, D, D, 0, 0, 0);

    // keys split (keys are already B^T layout for GEMM2)
    split_f32<<<dim3((unsigned)(BT / 2048)), blk, 0, stream>>>(keys, k_hi, k_lo, BT);

    // GEMM2: logits = qW @ keys^T + mask -> d_out score region (fp32)
    gemm_bt<true, 1><<<dim3(8, 8, B), blk, 0, stream>>>(
        qw_hi, qw_lo, k_hi, k_lo, score_f, nullptr, nullptr, mask,
        T, T, D, MAT, MAT, MAT);

    // V^T bf16 (B operand of GEMM3)
    transpose_split<<<dim3(32, 32, B), blk, 0, stream>>>(values, vt, nullptr, T, D, MAT, MAT);

    // softmax rows in place + bf16 copy
    softmax_rows<<<B * T, blk, 0, stream>>>(score_f, sc_bf);

    // GEMM3: ctx = score @ values (plain bf16)
    gemm_bt<false, 0><<<dim3(8, 8, B), blk, 0, stream>>>(
        sc_bf, nullptr, vt, nullptr, ctx_f, nullptr, nullptr, nullptr,
        T, D, T, MAT, MAT, MAT);
}

// Round 3
// 486.471 us; speedup vs baseline: 1.2510x; 1.2168x over previous
//
#include <hip/hip_runtime.h>
#include <hip/hip_bf16.h>

typedef _Float16 f16;
typedef __attribute__((ext_vector_type(8))) _Float16 half8;
typedef __attribute__((ext_vector_type(4))) float f32x4;

#define BM 128
#define BN 128
#define BK 32

// async global->LDS, 16B per lane; LDS dest is wave-uniform base + lane*16
__device__ __forceinline__ void gl2lds16(const f16* g, const f16* l) {
    __builtin_amdgcn_global_load_lds(
        (const __attribute__((address_space(1))) unsigned int*)g,
        (__attribute__((address_space(3))) unsigned int*)l, 16, 0, 0);
}

// ---------------------------------------------------------------------------
// Elementwise cast fp32 -> fp16, 8 elems/thread
// ---------------------------------------------------------------------------
__global__ __launch_bounds__(256)
void cast_f16(const float* __restrict__ in, f16* __restrict__ out, long long n) {
    long long i = ((long long)blockIdx.x * 256 + threadIdx.x) * 8;
    if (i >= n) return;
    float4 a = *(const float4*)&in[i];
    float4 b = *(const float4*)&in[i + 4];
    union { f16 h[8]; uint4 q; } H;
    H.h[0] = (f16)a.x; H.h[1] = (f16)a.y; H.h[2] = (f16)a.z; H.h[3] = (f16)a.w;
    H.h[4] = (f16)b.x; H.h[5] = (f16)b.y; H.h[6] = (f16)b.z; H.h[7] = (f16)b.w;
    *(uint4*)&out[i] = H.q;
}

// ---------------------------------------------------------------------------
// Transpose + cast: fp32 [R][C] -> fp16 [C][R]
// ---------------------------------------------------------------------------
__global__ __launch_bounds__(256)
void transpose_f16(const float* __restrict__ in, f16* __restrict__ out,
                   int R, int C, long long in_stride, long long out_stride) {
    const int b = blockIdx.z;
    in += (size_t)b * in_stride;
    out += (size_t)b * out_stride;

    __shared__ float tile[32][33];
    const int r0 = blockIdx.y * 32, c0 = blockIdx.x * 32;
    const int t = threadIdx.x;
    const int tr = t >> 5, tc = t & 31;
    for (int i = 0; i < 4; i++)
        tile[tr + i * 8][tc] = in[(size_t)(r0 + tr + i * 8) * C + c0 + tc];
    __syncthreads();
    for (int i = 0; i < 4; i++) {
        float v = tile[tc][tr + i * 8];
        out[(size_t)(c0 + tr + i * 8) * R + r0 + tc] = (f16)v;
    }
}

// ---------------------------------------------------------------------------
// B^T-layout fp16 GEMM, global_load_lds staging:
//   C[m][n] = sum_k A[m][k]*B[n][k]    (lda=ldb=K, ldc=N)
//   EPI: 0 = fp32 store; 1 = fp32 + mask[n]; 2 = fp16 store
// ---------------------------------------------------------------------------
template<int EPI>
__global__ __launch_bounds__(256)
void gemm_f16(const f16* __restrict__ A_, const f16* __restrict__ B_,
              float* __restrict__ Cf, f16* __restrict__ Ch,
              const float* __restrict__ mask,
              int M, int N, int K,
              long long batchA, long long batchB, long long batchC) {
    const int b = blockIdx.z;
    const int m0 = blockIdx.y * BM;
    const int n0 = blockIdx.x * BN;
    const int t = threadIdx.x;
    const int lane = t & 63, wv = t >> 6;
    const int wm = (wv >> 1) * 64, wn = (wv & 1) * 64;

    const f16* A = A_ + (size_t)b * batchA;
    const f16* B = B_ + (size_t)b * batchB;

    __shared__ alignas(16) f16 sA[BM][BK];
    __shared__ alignas(16) f16 sB[BN][BK];

    f32x4 acc[4][4];
    for (int mi = 0; mi < 4; mi++)
        for (int ni = 0; ni < 4; ni++)
            for (int r = 0; r < 4; r++) acc[mi][ni][r] = 0.0f;

    const int lrow = lane >> 2;        // 0..15
    const int lcol = (lane & 3) * 8;   // 0,8,16,24

    for (int k0 = 0; k0 < K; k0 += BK) {
#pragma unroll
        for (int i = 0; i < 2; i++) {
            const int r0 = (wv + 4 * i) * 16;       // wave-uniform row block
            gl2lds16(&A[(size_t)(m0 + r0 + lrow) * K + k0 + lcol], &sA[r0][0]);
            gl2lds16(&B[(size_t)(n0 + r0 + lrow) * K + k0 + lcol], &sB[r0][0]);
        }
        __syncthreads();

        const int fr = lane & 15, fq = (lane >> 4) * 8;
        half8 af[4], bf[4];
#pragma unroll
        for (int i = 0; i < 4; i++) {
            af[i] = *(const half8*)&sA[wm + i * 16 + fr][fq];
            bf[i] = *(const half8*)&sB[wn + i * 16 + fr][fq];
        }
#pragma unroll
        for (int mi = 0; mi < 4; mi++)
#pragma unroll
            for (int ni = 0; ni < 4; ni++)
                acc[mi][ni] = __builtin_amdgcn_mfma_f32_16x16x32_f16(af[mi], bf[ni], acc[mi][ni], 0, 0, 0);
        __syncthreads();
    }

    const int fr = lane & 15, q4 = (lane >> 4) * 4;
    for (int mi = 0; mi < 4; mi++)
        for (int ni = 0; ni < 4; ni++) {
            const int col = n0 + wn + ni * 16 + fr;
            float mv = 0.0f;
            if constexpr (EPI == 1) mv = mask[(size_t)b * N + col];
            for (int r = 0; r < 4; r++) {
                const int row = m0 + wm + mi * 16 + q4 + r;
                float v = acc[mi][ni][r];
                const size_t idx = (size_t)b * batchC + (size_t)row * N + col;
                if constexpr (EPI == 0) {
                    Cf[idx] = v;
                } else if constexpr (EPI == 1) {
                    Cf[idx] = v + mv;
                } else {
                    Ch[idx] = (f16)v;
                }
            }
        }
}

// ---------------------------------------------------------------------------
// Row softmax over 1024 cols, in place (fp32) + fp16 copy for the PV GEMM
// ---------------------------------------------------------------------------
__global__ __launch_bounds__(256)
void softmax_rows(float* __restrict__ w, f16* __restrict__ sb) {
    const size_t row = blockIdx.x;
    float* p = w + row * 1024;
    const int t = threadIdx.x;
    const int wv = t >> 6, ln = t & 63;

    float4 v = *(const float4*)&p[t * 4];
    float m = fmaxf(fmaxf(v.x, v.y), fmaxf(v.z, v.w));
    for (int o = 32; o > 0; o >>= 1) m = fmaxf(m, __shfl_down(m, o));
    __shared__ float redm[4];
    if (ln == 0) redm[wv] = m;
    __syncthreads();
    m = fmaxf(fmaxf(redm[0], redm[1]), fmaxf(redm[2], redm[3]));

    float e0 = __expf(v.x - m), e1 = __expf(v.y - m);
    float e2 = __expf(v.z - m), e3 = __expf(v.w - m);
    float s = e0 + e1 + e2 + e3;
    for (int o = 32; o > 0; o >>= 1) s += __shfl_down(s, o);
    __shared__ float reds[4];
    if (ln == 0) reds[wv] = s;
    __syncthreads();
    s = reds[0] + reds[1] + reds[2] + reds[3];
    const float inv = 1.0f / s;

    float4 o4; o4.x = e0 * inv; o4.y = e1 * inv; o4.z = e2 * inv; o4.w = e3 * inv;
    *(float4*)&p[t * 4] = o4;
    union { f16 h[4]; uint2 q; } H;
    H.h[0] = (f16)o4.x; H.h[1] = (f16)o4.y; H.h[2] = (f16)o4.z; H.h[3] = (f16)o4.w;
    *(uint2*)&sb[row * 1024 + t * 4] = H.q;
}

// ---------------------------------------------------------------------------
extern "C" void kernel_launch(void* const* d_in, const int* in_sizes, int n_in,
                              void* d_out, int out_size, void* d_ws, size_t ws_size,
                              hipStream_t stream) {
    const int B = 16, T = 1024, D = 1024;
    const long long MAT = (long long)T * D;      // 1M elems
    const long long BT = (long long)B * MAT;     // 16M elems

    const float* query  = (const float*)d_in[0]; // [B,TQ,DQ]
    const float* keys   = (const float*)d_in[1]; // [B,TK,DK]
    const float* values = (const float*)d_in[2]; // [B,TK,DV]
    const float* W      = (const float*)d_in[3]; // [DQ,DK]
    const float* mask   = (const float*)d_in[4]; // [B,TK]

    float* out = (float*)d_out;
    float* score_f = out;                        // [B,TQ,TK]
    float* ctx_f   = out + (size_t)BT;           // [B,TQ,DV]

    // Workspace (98 MB), stream-order aliasing:
    //   R1 (32 MB): q_f16  -> vt_f16
    //   R2 (32 MB): k_f16  -> sc_f16
    //   R3 (32 MB): qw_f16
    //   R4 ( 2 MB): wt_f16
    char* ws = (char*)d_ws;
    f16* R1  = (f16*)ws;                   ws += (size_t)BT * 2;
    f16* R2  = (f16*)ws;                   ws += (size_t)BT * 2;
    f16* qw  = (f16*)ws;                   ws += (size_t)BT * 2;
    f16* wt  = (f16*)ws;                   ws += (size_t)MAT * 2;

    f16* qf = R1, *vt = R1;
    f16* kf = R2, *sc = R2;

    dim3 blk(256);

    // casts / transposes
    cast_f16<<<dim3((unsigned)(BT / 2048)), blk, 0, stream>>>(query, qf, BT);
    transpose_f16<<<dim3(32, 32, 1), blk, 0, stream>>>(W, wt, D, D, 0, 0);

    // GEMM1: qW = query @ W  -> qw (fp16)
    gemm_f16<2><<<dim3(8, 128, 1), blk, 0, stream>>>(
        qf, wt, nullptr, qw, nullptr, B * T, D, D, 0, 0, 0);

    cast_f16<<<dim3((unsigned)(BT / 2048)), blk, 0, stream>>>(keys, kf, BT);

    // GEMM2: logits = qW @ keys^T + mask -> d_out score region (fp32)
    gemm_f16<1><<<dim3(8, 8, B), blk, 0, stream>>>(
        qw, kf, score_f, nullptr, mask, T, T, D, MAT, MAT, MAT);

    // V^T fp16 (B operand of GEMM3)
    transpose_f16<<<dim3(32, 32, B), blk, 0, stream>>>(values, vt, T, D, MAT, MAT);

    // softmax rows in place + fp16 copy
    softmax_rows<<<B * T, blk, 0, stream>>>(score_f, sc);

    // GEMM3: ctx = score @ values
    gemm_f16<0><<<dim3(8, 8, B), blk, 0, stream>>>(
        sc, vt, ctx_f, nullptr, nullptr, T, D, T, MAT, MAT, MAT);
}